// Round 3
// baseline (510.092 us; speedup 1.0000x reference)
//
#include <hip/hip_runtime.h>
#include <float.h>

typedef __attribute__((ext_vector_type(8))) short bf16x8;
typedef __attribute__((ext_vector_type(4))) short bf16x4;
typedef __attribute__((ext_vector_type(4))) float f32x4;

static __device__ __forceinline__ float bf2f(unsigned int u16) {
    return __uint_as_float(u16 << 16);
}
static __device__ __forceinline__ unsigned int f2bf(float f) {
    unsigned int u = __float_as_uint(f);
    return (u + 0x7FFFu + ((u >> 16) & 1u)) >> 16;  // RNE
}
static __device__ __forceinline__ unsigned int pack2(float lo, float hi) {
    return f2bf(lo) | (f2bf(hi) << 16);
}

// ---------- MFMA GEMM: C[rows x NC] = A_f32[rows x 256] @ W_f32[256 x NC] + bias, C stored bf16 ----------
// Block: 128 rows x 64 cols, 4 waves in 2x2 grid, each wave 64x32 (4x2 fragments of 16x16), K-step 32.
// As[128][36] bf16 row-major [row][k]; Ws[64][36] bf16 TRANSPOSED [col][k] so B-frags are contiguous.
template<int NC>
__global__ __launch_bounds__(256) void gemm_mfma(
    const float* __restrict__ A, const float* __restrict__ W,
    const float* __restrict__ bias, unsigned short* __restrict__ C)
{
    const int nbn = NC >> 6;
    const int bn = blockIdx.x % nbn;
    const int bm = blockIdx.x / nbn;
    const size_t r0 = (size_t)bm * 128;
    const int c0 = bn << 6;

    __shared__ __align__(16) unsigned short As[128][36];
    __shared__ __align__(16) unsigned short Ws[64][36];

    const int t = threadIdx.x;
    const int wave = t >> 6, lane = t & 63;
    const int wr = wave >> 1, wc = wave & 1;
    const int row0 = wr * 64, col0 = wc * 32;
    const int lr = lane & 15;          // fragment row (A) / col (B) / col (C)
    const int kh = lane >> 4;          // k-half: k = kh*8 .. kh*8+7

    f32x4 acc[4][2];
    #pragma unroll
    for (int i = 0; i < 4; ++i)
        #pragma unroll
        for (int j = 0; j < 2; ++j) acc[i][j] = (f32x4){0.f, 0.f, 0.f, 0.f};

    const int ar = t >> 1, aks = (t & 1) * 16;       // A stage: row ar, k aks..aks+15
    const int wk = t >> 3, wcs = (t & 7) * 8;        // W stage: k-row wk, cols wcs..wcs+7

    for (int k0 = 0; k0 < 256; k0 += 32) {
        const float4 a0 = *(const float4*)(A + (r0 + ar) * 256 + k0 + aks);
        const float4 a1 = *(const float4*)(A + (r0 + ar) * 256 + k0 + aks + 4);
        const float4 a2 = *(const float4*)(A + (r0 + ar) * 256 + k0 + aks + 8);
        const float4 a3 = *(const float4*)(A + (r0 + ar) * 256 + k0 + aks + 12);
        const float4 w0 = *(const float4*)(W + (size_t)(k0 + wk) * NC + c0 + wcs);
        const float4 w1 = *(const float4*)(W + (size_t)(k0 + wk) * NC + c0 + wcs + 4);
        __syncthreads();   // previous iteration's LDS reads complete
        {
            unsigned int* dst = (unsigned int*)&As[ar][aks];
            dst[0] = pack2(a0.x, a0.y); dst[1] = pack2(a0.z, a0.w);
            dst[2] = pack2(a1.x, a1.y); dst[3] = pack2(a1.z, a1.w);
            dst[4] = pack2(a2.x, a2.y); dst[5] = pack2(a2.z, a2.w);
            dst[6] = pack2(a3.x, a3.y); dst[7] = pack2(a3.z, a3.w);
        }
        {
            const float wf[8] = {w0.x, w0.y, w0.z, w0.w, w1.x, w1.y, w1.z, w1.w};
            #pragma unroll
            for (int e = 0; e < 8; ++e)
                Ws[wcs + e][wk] = (unsigned short)f2bf(wf[e]);   // transposed scatter
        }
        __syncthreads();

        bf16x8 bfr[2];
        #pragma unroll
        for (int j = 0; j < 2; ++j) {
            const bf16x4 lo = *(const bf16x4*)&Ws[col0 + j*16 + lr][kh * 8];
            const bf16x4 hi = *(const bf16x4*)&Ws[col0 + j*16 + lr][kh * 8 + 4];
            bfr[j] = __builtin_shufflevector(lo, hi, 0, 1, 2, 3, 4, 5, 6, 7);
        }
        #pragma unroll
        for (int i = 0; i < 4; ++i) {
            const bf16x4 lo = *(const bf16x4*)&As[row0 + i*16 + lr][kh * 8];
            const bf16x4 hi = *(const bf16x4*)&As[row0 + i*16 + lr][kh * 8 + 4];
            const bf16x8 afr = __builtin_shufflevector(lo, hi, 0, 1, 2, 3, 4, 5, 6, 7);
            acc[i][0] = __builtin_amdgcn_mfma_f32_16x16x32_bf16(afr, bfr[0], acc[i][0], 0, 0, 0);
            acc[i][1] = __builtin_amdgcn_mfma_f32_16x16x32_bf16(afr, bfr[1], acc[i][1], 0, 0, 0);
        }
    }

    // C: row = row0 + i*16 + (lane>>4)*4 + q, col = c0 + col0 + j*16 + (lane&15)
    #pragma unroll
    for (int i = 0; i < 4; ++i) {
        #pragma unroll
        for (int j = 0; j < 2; ++j) {
            const int col = c0 + col0 + j*16 + lr;
            const float bb = bias[col];
            #pragma unroll
            for (int q = 0; q < 4; ++q) {
                const int row = row0 + i*16 + kh*4 + q;
                C[(r0 + row) * NC + col] = (unsigned short)f2bf(acc[i][j][q] + bb);
            }
        }
    }
}

// ---------- fused attention: one block per (window, head) ----------
__global__ __launch_bounds__(256) void attn_win(
    const unsigned short* __restrict__ qbf, const unsigned short* __restrict__ kvbf,
    const float* __restrict__ bias_table, const int* __restrict__ mask_left,
    const int* __restrict__ mask_right, float* __restrict__ out)
{
    __shared__ __align__(16) float smem[8192 + 128*34 + 192];
    float* const qT   = smem;                 // [32][64]
    float* const kT   = smem + 2048;          // [32][128]
    float* const Ps   = smem;                 // [64][128] aliases qT/kT after barrier
    float* const Vs   = smem + 8192;          // [128][34]
    float* const bcol = smem + 8192 + 128*34; // [192]

    const int w = blockIdx.x >> 3;
    const int h = blockIdx.x & 7;
    const int t = threadIdx.x;

    {
        const int n = t >> 2, d0 = (t & 3) * 8;
        const uint4 u = *(const uint4*)(qbf + ((size_t)(w*64 + n))*256 + h*32 + d0);
        const unsigned int uu[4] = {u.x, u.y, u.z, u.w};
        #pragma unroll
        for (int i = 0; i < 4; ++i) {
            qT[(d0+2*i)  *64 + n] = bf2f(uu[i] & 0xFFFFu);
            qT[(d0+2*i+1)*64 + n] = bf2f(uu[i] >> 16);
        }
    }
    #pragma unroll
    for (int it = 0; it < 2; ++it) {
        const int idx = t + it*256;
        const int m = idx >> 2, d0 = (idx & 3) * 8;
        const unsigned short* kp = kvbf + ((size_t)(w*128 + m))*512 + h*32 + d0;
        const uint4 ku = *(const uint4*)kp;
        const uint4 vu = *(const uint4*)(kp + 256);
        const unsigned int k4[4] = {ku.x, ku.y, ku.z, ku.w};
        const unsigned int v4[4] = {vu.x, vu.y, vu.z, vu.w};
        #pragma unroll
        for (int i = 0; i < 4; ++i) {
            kT[(d0+2*i)  *128 + m] = bf2f(k4[i] & 0xFFFFu);
            kT[(d0+2*i+1)*128 + m] = bf2f(k4[i] >> 16);
            Vs[m*34 + d0 + 2*i]     = bf2f(v4[i] & 0xFFFFu);
            Vs[m*34 + d0 + 2*i + 1] = bf2f(v4[i] >> 16);
        }
    }
    if (t < 192) bcol[t] = bias_table[t*8 + h];
    __syncthreads();

    const int tx = t & 15, ty = t >> 4;
    float acc[4][8];
    #pragma unroll
    for (int i = 0; i < 4; ++i)
        #pragma unroll
        for (int j = 0; j < 8; ++j) acc[i][j] = 0.0f;

    #pragma unroll 8
    for (int d = 0; d < 32; ++d) {
        const float4 qv = *(const float4*)&qT[d*64 + ty*4];
        const float4 ka = *(const float4*)&kT[d*128 + tx*8];
        const float4 kb = *(const float4*)&kT[d*128 + tx*8 + 4];
        const float q4[4] = {qv.x, qv.y, qv.z, qv.w};
        const float k8[8] = {ka.x,ka.y,ka.z,ka.w,kb.x,kb.y,kb.z,kb.w};
        #pragma unroll
        for (int i = 0; i < 4; ++i)
            #pragma unroll
            for (int j = 0; j < 8; ++j)
                acc[i][j] = fmaf(q4[i], k8[j], acc[i][j]);
    }

    const int wi = w & 255;
    const int* mrow = nullptr;
    if (wi < 2) mrow = mask_left + wi * (64*128);
    else if (wi >= 254) mrow = mask_right + (wi - 254) * (64*128);
    const float scale = 0.17677669529663687f;
    #pragma unroll
    for (int i = 0; i < 4; ++i) {
        const int n = ty*4 + i;
        #pragma unroll
        for (int j = 0; j < 8; ++j) {
            const int m = tx*8 + j;
            acc[i][j] = fmaf(acc[i][j], scale, bcol[n - m + 128]);
        }
    }
    if (mrow) {
        #pragma unroll
        for (int i = 0; i < 4; ++i) {
            const int n = ty*4 + i;
            #pragma unroll
            for (int j = 0; j < 8; ++j) {
                if (mrow[n*128 + tx*8 + j] == 1) acc[i][j] = -FLT_MAX;
            }
        }
    }

    float inv[4];
    #pragma unroll
    for (int i = 0; i < 4; ++i) {
        float mx = acc[i][0];
        #pragma unroll
        for (int j = 1; j < 8; ++j) mx = fmaxf(mx, acc[i][j]);
        mx = fmaxf(mx, __shfl_xor(mx, 1));
        mx = fmaxf(mx, __shfl_xor(mx, 2));
        mx = fmaxf(mx, __shfl_xor(mx, 4));
        mx = fmaxf(mx, __shfl_xor(mx, 8));
        float sm = 0.0f;
        #pragma unroll
        for (int j = 0; j < 8; ++j) { acc[i][j] = __expf(acc[i][j] - mx); sm += acc[i][j]; }
        sm += __shfl_xor(sm, 1);
        sm += __shfl_xor(sm, 2);
        sm += __shfl_xor(sm, 4);
        sm += __shfl_xor(sm, 8);
        inv[i] = 1.0f / sm;
    }

    __syncthreads();
    #pragma unroll
    for (int i = 0; i < 4; ++i) {
        const float4 p0 = make_float4(acc[i][0]*inv[i], acc[i][1]*inv[i], acc[i][2]*inv[i], acc[i][3]*inv[i]);
        const float4 p1 = make_float4(acc[i][4]*inv[i], acc[i][5]*inv[i], acc[i][6]*inv[i], acc[i][7]*inv[i]);
        *(float4*)&Ps[(ty*4+i)*128 + tx*8]     = p0;
        *(float4*)&Ps[(ty*4+i)*128 + tx*8 + 4] = p1;
    }
    __syncthreads();

    float o[4][2];
    #pragma unroll
    for (int i = 0; i < 4; ++i) { o[i][0] = 0.0f; o[i][1] = 0.0f; }
    for (int m0 = 0; m0 < 128; m0 += 4) {
        float pe[4][4];
        #pragma unroll
        for (int i = 0; i < 4; ++i) {
            const float4 p = *(const float4*)&Ps[(ty*4+i)*128 + m0];
            pe[i][0] = p.x; pe[i][1] = p.y; pe[i][2] = p.z; pe[i][3] = p.w;
        }
        #pragma unroll
        for (int mm = 0; mm < 4; ++mm) {
            const float2 vv = *(const float2*)&Vs[(m0+mm)*34 + tx*2];
            #pragma unroll
            for (int i = 0; i < 4; ++i) {
                o[i][0] = fmaf(pe[i][mm], vv.x, o[i][0]);
                o[i][1] = fmaf(pe[i][mm], vv.y, o[i][1]);
            }
        }
    }
    #pragma unroll
    for (int i = 0; i < 4; ++i) {
        const int n = ty*4 + i;
        *(float2*)(out + ((size_t)(w*64 + n))*256 + h*32 + tx*2) = make_float2(o[i][0], o[i][1]);
    }
}

// ---------- in-place out-projection: IO[65536x256] = IO @ W[256x256] + b ----------
__global__ __launch_bounds__(256) void proj_inplace(
    float* __restrict__ IO, const float* __restrict__ W, const float* __restrict__ bias)
{
    const size_t r0 = (size_t)blockIdx.x * 64;
    __shared__ __align__(16) float As[16][64];
    __shared__ __align__(16) float Bs[16][256];
    const int t = threadIdx.x;
    const int tx = t & 31, ty = t >> 5;
    const int ar = t >> 2, ak = (t & 3) * 4;
    const int bk = t >> 4, bc = (t & 15) * 16;

    float acc[8][8];
    #pragma unroll
    for (int i = 0; i < 8; ++i)
        #pragma unroll
        for (int j = 0; j < 8; ++j) acc[i][j] = 0.0f;

    for (int k0 = 0; k0 < 256; k0 += 16) {
        const float4 av = *(const float4*)(IO + (r0 + ar) * 256 + k0 + ak);
        const float4 w0 = *(const float4*)(W + (size_t)(k0 + bk) * 256 + bc);
        const float4 w1 = *(const float4*)(W + (size_t)(k0 + bk) * 256 + bc + 4);
        const float4 w2 = *(const float4*)(W + (size_t)(k0 + bk) * 256 + bc + 8);
        const float4 w3 = *(const float4*)(W + (size_t)(k0 + bk) * 256 + bc + 12);
        __syncthreads();
        As[ak+0][ar] = av.x; As[ak+1][ar] = av.y; As[ak+2][ar] = av.z; As[ak+3][ar] = av.w;
        *(float4*)&Bs[bk][bc]      = w0;
        *(float4*)&Bs[bk][bc + 4]  = w1;
        *(float4*)&Bs[bk][bc + 8]  = w2;
        *(float4*)&Bs[bk][bc + 12] = w3;
        __syncthreads();
        #pragma unroll
        for (int kk = 0; kk < 16; ++kk) {
            const float4 x0 = *(const float4*)&As[kk][ty*8];
            const float4 x1 = *(const float4*)&As[kk][ty*8+4];
            const float a8[8] = {x0.x,x0.y,x0.z,x0.w,x1.x,x1.y,x1.z,x1.w};
            float b8[8];
            #pragma unroll
            for (int j = 0; j < 8; ++j) b8[j] = Bs[kk][tx + 32*j];
            #pragma unroll
            for (int i = 0; i < 8; ++i)
                #pragma unroll
                for (int j = 0; j < 8; ++j)
                    acc[i][j] = fmaf(a8[i], b8[j], acc[i][j]);
        }
    }
    float bb[8];
    #pragma unroll
    for (int j = 0; j < 8; ++j) bb[j] = bias[tx + 32*j];
    #pragma unroll
    for (int i = 0; i < 8; ++i)
        #pragma unroll
        for (int j = 0; j < 8; ++j)
            IO[(r0 + ty*8 + i) * 256 + tx + 32*j] = acc[i][j] + bb[j];
}

extern "C" void kernel_launch(void* const* d_in, const int* in_sizes, int n_in,
                              void* d_out, int out_size, void* d_ws, size_t ws_size,
                              hipStream_t stream)
{
    const float* x      = (const float*)d_in[0];   // (1024,64,256) f32
    const float* x_     = (const float*)d_in[1];   // (1024,128,256) f32
    const int*   mask_l = (const int*)d_in[2];
    const int*   mask_r = (const int*)d_in[3];
    const float* q_w    = (const float*)d_in[5];
    const float* q_b    = (const float*)d_in[6];
    const float* kv_w   = (const float*)d_in[7];
    const float* kv_b   = (const float*)d_in[8];
    const float* proj_w = (const float*)d_in[9];
    const float* proj_b = (const float*)d_in[10];
    const float* bias_t = (const float*)d_in[11];  // (192,8)

    // ws: q bf16 [65536][256] (32 MiB) | kv bf16 [131072][512] (128 MiB)
    unsigned short* qbf  = (unsigned short*)d_ws;
    unsigned short* kvbf = qbf + (size_t)65536 * 256;
    float* out = (float*)d_out;

    gemm_mfma<256><<<512 * 4, 256, 0, stream>>>(x,  q_w,  q_b,  qbf);
    gemm_mfma<512><<<1024 * 8, 256, 0, stream>>>(x_, kv_w, kv_b, kvbf);
    attn_win<<<8192, 256, 0, stream>>>(qbf, kvbf, bias_t, mask_l, mask_r, out);
    proj_inplace<<<1024, 256, 0, stream>>>(out, proj_w, proj_b);
}

// Round 5
// 312.943 us; speedup vs baseline: 1.6300x; 1.6300x over previous
//
#include <hip/hip_runtime.h>
#include <float.h>

// B_=1024 windows, N=64, M=128, H=8, D=32, DIM=256, nW=256
// rel bias index: rel = n - m + 128 in [1,191]
// masks: wi in {0,1} -> mask_left[wi], wi in {254,255} -> mask_right[wi-254]

typedef __attribute__((ext_vector_type(8))) short bf16x8;
typedef __attribute__((ext_vector_type(4))) float f32x4;

static __device__ __forceinline__ unsigned int f2bf(float f) {
    unsigned int u = __float_as_uint(f);
    return (u + 0x7FFFu + ((u >> 16) & 1u)) >> 16;  // RNE
}
static __device__ __forceinline__ unsigned int pack2(float lo, float hi) {
    return f2bf(lo) | (f2bf(hi) << 16);
}

// Transposed bf16 weights: [col][k], q @0 (256x256), kv @65536 (512x256), proj @196608 (256x256)
__device__ unsigned short g_Wt[262144];

__global__ __launch_bounds__(256) void prep_wt(
    const float* __restrict__ q_w, const float* __restrict__ kv_w, const float* __restrict__ proj_w)
{
    const int b = blockIdx.x, k = threadIdx.x;
    float v; unsigned short* dst;
    if (b < 256)      { v = q_w[k * 256 + b];            dst = g_Wt + b * 256; }
    else if (b < 768) { v = kv_w[k * 512 + (b - 256)];   dst = g_Wt + 65536 + (b - 256) * 256; }
    else              { v = proj_w[k * 256 + (b - 768)]; dst = g_Wt + 196608 + (b - 768) * 256; }
    dst[k] = (unsigned short)f2bf(v);
}

// ---------- single-stage MFMA GEMM: C[rows x NC] = A[rows x 256] @ W + bias ----------
// tile 128x128, K=256 entirely in LDS, 512 threads = 8 waves (4 row x 2 col), wave tile 32x64.
// LDS layout: linear [row][256] bf16 with XOR swizzle byte ^= ((row&7)<<4) -> all frag reads b128.
template<int NC, int WT_OFF, bool ABF16, bool F32OUT>
__global__ __launch_bounds__(512) void gemm_mfma(
    const void* __restrict__ Ain, const float* __restrict__ bias, void* __restrict__ Cout)
{
    __shared__ __align__(16) unsigned short As[128 * 256];
    __shared__ __align__(16) unsigned short Ws[128 * 256];
    const int nbn = NC / 128;
    const int bm = blockIdx.x / nbn, bn = blockIdx.x % nbn;
    const size_t r0 = (size_t)bm * 128;
    const int c0 = bn * 128;
    const int t = threadIdx.x;
    const int wave = t >> 6, lane = t & 63;
    const int lr = lane & 15, hi = lane >> 4;
    const int rw = (wave >> 1) * 32, cw = (wave & 1) * 64;

    // stage A: thread -> row=t>>2, a=t&3; interleaved k so LDS write banks spread
    {
        const int row = t >> 2, a = t & 3;
        char* dst = (char*)As + row * 512;
        const int swz = (row & 7) << 4;
        if (ABF16) {
            const unsigned short* src = (const unsigned short*)Ain + (r0 + row) * 256;
            #pragma unroll
            for (int i = 0; i < 8; ++i) {
                const int k = 8 * a + 32 * i;
                const uint4 v = *(const uint4*)(src + k);
                *(uint4*)(dst + ((2 * k) ^ swz)) = v;
            }
        } else {
            const float* src = (const float*)Ain + (r0 + row) * 256;
            #pragma unroll
            for (int i = 0; i < 16; ++i) {
                const int k = 4 * a + 16 * i;
                const float4 v = *(const float4*)(src + k);
                uint2 u; u.x = pack2(v.x, v.y); u.y = pack2(v.z, v.w);
                *(uint2*)(dst + ((2 * k) ^ swz)) = u;
            }
        }
    }
    // stage W (already transposed bf16 [col][k])
    {
        const int col = t >> 2, a = t & 3;
        const unsigned short* src = g_Wt + WT_OFF + (size_t)(c0 + col) * 256;
        char* dst = (char*)Ws + col * 512;
        const int swz = (col & 7) << 4;
        #pragma unroll
        for (int i = 0; i < 8; ++i) {
            const int k = 8 * a + 32 * i;
            const uint4 v = *(const uint4*)(src + k);
            *(uint4*)(dst + ((2 * k) ^ swz)) = v;
        }
    }
    __syncthreads();

    f32x4 acc[2][4];
    #pragma unroll
    for (int ai = 0; ai < 2; ++ai)
        #pragma unroll
        for (int bj = 0; bj < 4; ++bj) acc[ai][bj] = (f32x4){0.f, 0.f, 0.f, 0.f};

    const int swzr = (lr & 7) << 4;  // (row&7)==(lr&7) since rw, ai*16 are multiples of 8
    #pragma unroll
    for (int kk = 0; kk < 8; ++kk) {
        const int ko = (64 * kk + 16 * hi) ^ swzr;
        bf16x8 af[2], bfr[4];
        #pragma unroll
        for (int ai = 0; ai < 2; ++ai)
            af[ai] = *(const bf16x8*)((char*)As + (rw + ai * 16 + lr) * 512 + ko);
        #pragma unroll
        for (int bj = 0; bj < 4; ++bj)
            bfr[bj] = *(const bf16x8*)((char*)Ws + (cw + bj * 16 + lr) * 512 + ko);
        #pragma unroll
        for (int ai = 0; ai < 2; ++ai)
            #pragma unroll
            for (int bj = 0; bj < 4; ++bj)
                acc[ai][bj] = __builtin_amdgcn_mfma_f32_16x16x32_bf16(af[ai], bfr[bj], acc[ai][bj], 0, 0, 0);
    }

    // epilogue: C row = rw+ai*16+4*hi+q, col = cw+bj*16+lr
    #pragma unroll
    for (int ai = 0; ai < 2; ++ai) {
        #pragma unroll
        for (int bj = 0; bj < 4; ++bj) {
            const int col = c0 + cw + bj * 16 + lr;
            const float bb = bias[col];
            #pragma unroll
            for (int q = 0; q < 4; ++q) {
                const size_t row = r0 + rw + ai * 16 + 4 * hi + q;
                const float val = acc[ai][bj][q] + bb;
                if (F32OUT) ((float*)Cout)[row * NC + col] = val;
                else        ((unsigned short*)Cout)[row * NC + col] = (unsigned short)f2bf(val);
            }
        }
    }
}

// ---------- fused MFMA attention: one block per WINDOW, loop over 8 heads ----------
// Writes bf16 attn output back into the q buffer region (block-local rows -> race-free).
__global__ __launch_bounds__(256) void attn_fused(
    const unsigned short* __restrict__ qbf, const unsigned short* __restrict__ kvbf,
    const float* __restrict__ bias_table, const int* __restrict__ mask_left,
    const int* __restrict__ mask_right, unsigned short* __restrict__ aout)
{
    __shared__ __align__(16) unsigned short Qn[64 * 32];    // [n][d] natural
    __shared__ __align__(16) unsigned short Kn[128 * 32];   // [m][d] natural
    __shared__ __align__(16) unsigned short Vt[32 * 128];   // [d][m], swizzled ^((d&7)<<4)
    __shared__ __align__(16) unsigned short Pn[64 * 128];   // [n][m], swizzled ^((n&7)<<4)
    __shared__ float ballT[8 * 192];                        // bias table [h][rel]

    const int w = blockIdx.x;
    const int t = threadIdx.x;
    const int wave = t >> 6, lane = t & 63;
    const int lr = lane & 15, hi = lane >> 4;
    const int n0w = wave * 16;

    for (int i = t; i < 1536; i += 256) {
        const int hh = i / 192, r = i - hh * 192;
        ballT[i] = bias_table[r * 8 + hh];
    }

    const int wi = w & 255;
    const int* mbase = nullptr;
    if (wi < 2) mbase = mask_left + wi * (64 * 128);
    else if (wi >= 254) mbase = mask_right + (wi - 254) * (64 * 128);

    const float scale = 0.17677669529663687f;  // 32^-0.5

    for (int h = 0; h < 8; ++h) {
        __syncthreads();   // prior iteration's LDS reads complete (and ballT before first use)
        {   // stage Q head-slice: [64][32]
            const int n = t >> 2, dq = t & 3;
            const uint4 v = *(const uint4*)(qbf + ((size_t)(w * 64 + n)) * 256 + h * 32 + dq * 8);
            *(uint4*)((char*)Qn + n * 64 + dq * 16) = v;
        }
        #pragma unroll
        for (int i = 0; i < 2; ++i) {   // stage K: [128][32]
            const int m = (t >> 2) + 64 * i, dq = t & 3;
            const uint4 v = *(const uint4*)(kvbf + ((size_t)(w * 128 + m)) * 512 + h * 32 + dq * 8);
            *(uint4*)((char*)Kn + m * 64 + dq * 16) = v;
        }
        #pragma unroll
        for (int i = 0; i < 2; ++i) {   // stage V transposed: Vt[d][m] swizzled
            const int db = (t >> 7) * 2 + i, m = t & 127;
            const uint4 v = *(const uint4*)(kvbf + ((size_t)(w * 128 + m)) * 512 + 256 + h * 32 + db * 8);
            const unsigned short* vs = (const unsigned short*)&v;
            #pragma unroll
            for (int e = 0; e < 8; ++e) {
                const int d = db * 8 + e;
                *(unsigned short*)((char*)Vt + d * 256 + ((2 * m) ^ ((d & 7) << 4))) = vs[e];
            }
        }
        __syncthreads();

        // S = Q K^T : wave handles rows n0w..n0w+15, all 128 cols
        const bf16x8 qa = *(const bf16x8*)((char*)Qn + (n0w + lr) * 64 + 16 * hi);
        f32x4 sacc[8];
        #pragma unroll
        for (int mj = 0; mj < 8; ++mj) {
            sacc[mj] = (f32x4){0.f, 0.f, 0.f, 0.f};
            const bf16x8 kb = *(const bf16x8*)((char*)Kn + (mj * 16 + lr) * 64 + 16 * hi);
            sacc[mj] = __builtin_amdgcn_mfma_f32_16x16x32_bf16(qa, kb, sacc[mj], 0, 0, 0);
        }

        // epilogue on C-layout: row n = n0w + 4*hi + q, col m = 16*mj + lr
        const float* bh = ballT + h * 192;
        #pragma unroll
        for (int mj = 0; mj < 8; ++mj) {
            const int m = 16 * mj + lr;
            #pragma unroll
            for (int q = 0; q < 4; ++q) {
                const int n = n0w + 4 * hi + q;
                sacc[mj][q] = fmaf(sacc[mj][q], scale, bh[n - m + 128]);
            }
        }
        if (mbase) {
            #pragma unroll
            for (int mj = 0; mj < 8; ++mj) {
                const int m = 16 * mj + lr;
                #pragma unroll
                for (int q = 0; q < 4; ++q) {
                    const int n = n0w + 4 * hi + q;
                    if (mbase[n * 128 + m] == 1) sacc[mj][q] = -FLT_MAX;
                }
            }
        }

        // softmax over m (per row): row lives in 16 lanes sharing hi -> shfl_xor 1,2,4,8
        float inv[4];
        #pragma unroll
        for (int q = 0; q < 4; ++q) {
            float mx = sacc[0][q];
            #pragma unroll
            for (int mj = 1; mj < 8; ++mj) mx = fmaxf(mx, sacc[mj][q]);
            mx = fmaxf(mx, __shfl_xor(mx, 1));
            mx = fmaxf(mx, __shfl_xor(mx, 2));
            mx = fmaxf(mx, __shfl_xor(mx, 4));
            mx = fmaxf(mx, __shfl_xor(mx, 8));
            float sm = 0.f;
            #pragma unroll
            for (int mj = 0; mj < 8; ++mj) {
                sacc[mj][q] = __expf(sacc[mj][q] - mx);
                sm += sacc[mj][q];
            }
            sm += __shfl_xor(sm, 1);
            sm += __shfl_xor(sm, 2);
            sm += __shfl_xor(sm, 4);
            sm += __shfl_xor(sm, 8);
            inv[q] = 1.0f / sm;
        }

        // write unnormalized P bf16 to Pn (pair even/odd lanes -> u32 stores); wave-local rows
        #pragma unroll
        for (int mj = 0; mj < 8; ++mj) {
            #pragma unroll
            for (int q = 0; q < 4; ++q) {
                const float pv = sacc[mj][q];
                const float po = __shfl_xor(pv, 1);
                if (!(lane & 1)) {
                    const int n = n0w + 4 * hi + q;
                    const int m = 16 * mj + lr;   // even
                    const unsigned int u = f2bf(pv) | (f2bf(po) << 16);
                    *(unsigned int*)((char*)Pn + n * 256 + ((2 * m) ^ ((n & 7) << 4))) = u;
                }
            }
        }
        // no barrier needed: each wave reads only its own Pn rows (compiler orders same-wave LDS)

        // O = P V : rows n0w..+15, cols d 0..31 (j=0,1)
        f32x4 oacc[2];
        oacc[0] = (f32x4){0.f, 0.f, 0.f, 0.f};
        oacc[1] = (f32x4){0.f, 0.f, 0.f, 0.f};
        const int nA = n0w + lr;                 // A-frag row
        const int swzA = (nA & 7) << 4;
        #pragma unroll
        for (int kk = 0; kk < 4; ++kk) {
            const bf16x8 pa = *(const bf16x8*)((char*)Pn + nA * 256 + ((64 * kk + 16 * hi) ^ swzA));
            #pragma unroll
            for (int j = 0; j < 2; ++j) {
                const int d = j * 16 + lr;
                const bf16x8 vb = *(const bf16x8*)((char*)Vt + d * 256 + ((64 * kk + 16 * hi) ^ ((d & 7) << 4)));
                oacc[j] = __builtin_amdgcn_mfma_f32_16x16x32_bf16(pa, vb, oacc[j], 0, 0, 0);
            }
        }
        // store bf16 into aout (the q region): row n = n0w+4*hi+q, col h*32 + j*16 + lr
        #pragma unroll
        for (int j = 0; j < 2; ++j) {
            #pragma unroll
            for (int q = 0; q < 4; ++q) {
                const int n = n0w + 4 * hi + q;
                aout[((size_t)(w * 64 + n)) * 256 + h * 32 + j * 16 + lr] =
                    (unsigned short)f2bf(oacc[j][q] * inv[q]);
            }
        }
    }
}

extern "C" void kernel_launch(void* const* d_in, const int* in_sizes, int n_in,
                              void* d_out, int out_size, void* d_ws, size_t ws_size,
                              hipStream_t stream)
{
    const float* x      = (const float*)d_in[0];   // (1024,64,256) f32
    const float* x_     = (const float*)d_in[1];   // (1024,128,256) f32
    const int*   mask_l = (const int*)d_in[2];
    const int*   mask_r = (const int*)d_in[3];
    const float* q_w    = (const float*)d_in[5];
    const float* q_b    = (const float*)d_in[6];
    const float* kv_w   = (const float*)d_in[7];
    const float* kv_b   = (const float*)d_in[8];
    const float* proj_w = (const float*)d_in[9];
    const float* proj_b = (const float*)d_in[10];
    const float* bias_t = (const float*)d_in[11];  // (192,8)

    // ws: qbf bf16 [65536][256] (32 MiB; later overwritten with bf16 attn-out) | kvbf bf16 [131072][512] (128 MiB)
    unsigned short* qbf  = (unsigned short*)d_ws;
    unsigned short* kvbf = qbf + (size_t)65536 * 256;
    float* out = (float*)d_out;

    prep_wt<<<1024, 256, 0, stream>>>(q_w, kv_w, proj_w);
    gemm_mfma<256, 0,      false, false><<<1024, 512, 0, stream>>>(x,  q_b,  qbf);
    gemm_mfma<512, 65536,  false, false><<<4096, 512, 0, stream>>>(x_, kv_b, kvbf);
    attn_fused<<<1024, 256, 0, stream>>>(qbf, kvbf, bias_t, mask_l, mask_r, qbf);
    gemm_mfma<256, 196608, true,  true ><<<1024, 512, 0, stream>>>(qbf, proj_b, out);
}